// Round 15
// baseline (149.355 us; speedup 1.0000x reference)
//
#include <hip/hip_runtime.h>

#define N_NODES 50000
#define N_EDGES 800000
#define N_GRAPHS 512
#define FDIM 128
#define NTYPES_PAD 1000

#define NBLK 128
#define CHUNK ((N_EDGES + NBLK - 1) / NBLK)  // 6250
#define NQUAD (N_NODES / 4)                  // 12500
#define NSB ((NQUAD + 255) / 256)            // 49 scan blocks in k_prep
#define EMBW_BLOCKS 16
#define NPW 2
#define NW ((N_NODES + NPW - 1) / NPW)       // 25000

typedef __bf16 bf16x8 __attribute__((ext_vector_type(8)));
typedef float f32x4 __attribute__((ext_vector_type(4)));
union BF8 { bf16x8 v; unsigned short u[8]; };

__device__ __forceinline__ unsigned short f2bf(float f) {
  unsigned int u = __float_as_uint(f);
  unsigned int r = (u + 0x7FFFu + ((u >> 16) & 1u)) >> 16;
  return (unsigned short)r;
}
__device__ __forceinline__ float bflo(unsigned int v) {
  return __uint_as_float(v << 16);
}
__device__ __forceinline__ float bfhi(unsigned int v) {
  return __uint_as_float(v & 0xFFFF0000u);
}

// Per-chunk LDS histogram (8-bit packed); emits per-edge local rank.
// Also resets k_prep's done-counter for this launch (graph replays).
__global__ __launch_bounds__(512) void k_hist(const int* __restrict__ dst,
                                              unsigned int* __restrict__ Hist,
                                              unsigned char* __restrict__ rank8,
                                              int* __restrict__ g_done) {
  __shared__ unsigned int h[NQUAD];  // 50 KB
  int b = blockIdx.x, t = threadIdx.x;
  if (b == 0 && t == 0) *g_done = 0;
  for (int i = t; i < NQUAD; i += 512) h[i] = 0;
  __syncthreads();
  int e0 = b * CHUNK, e1 = min(e0 + CHUNK, N_EDGES);
  for (int e = e0 + t; e < e1; e += 512) {
    int d = dst[e];
    unsigned int sh = (d & 3) * 8;
    unsigned int old = atomicAdd(&h[d >> 2], 1u << sh);
    rank8[e] = (unsigned char)((old >> sh) & 0xFFu);
  }
  __syncthreads();
  unsigned int* H = Hist + (size_t)b * NQUAD;
  for (int i = t; i < NQUAD; i += 512) H[i] = h[i];
}

// Fused kernel: blocks [0,NSB) do the scan/prep work (Cur bases, dis,
// row_ptr via device-scope all-posted barrier, Zb zero, gstart); blocks
// [NSB, NSB+EMBW_BLOCKS) compute T1 = emb @ W1 (independent work).
__global__ __launch_bounds__(256) void k_prep(
    const unsigned int* __restrict__ Hist, const int* __restrict__ batch,
    unsigned int* __restrict__ Cur, float* __restrict__ dis,
    int* __restrict__ row_ptr, float* __restrict__ Zb,
    int* __restrict__ gstart, int* __restrict__ g_bsum,
    int* __restrict__ g_done, const float* __restrict__ emb,
    const float* __restrict__ W1, unsigned short* __restrict__ T1) {
  __shared__ unsigned short sh[16384];  // 32 KB union (embw Ws / prep scan)
  int blk = blockIdx.x, tid = threadIdx.x;

  if (blk >= NSB) {
    // ---- embw part: T1 = emb @ W1, swizzled bf16 W in LDS ----
    unsigned short* Ws = sh;
    int t = tid, w = t >> 6, l = t & 63;
    for (int i = t; i < 16384; i += 256) {
      int k = i >> 7, n = i & 127;
      Ws[n * 128 + (k ^ ((n & 15) << 3))] = f2bf(W1[i]);
    }
    int row0 = (blk - NSB) * 64 + w * 16;
    int arow = row0 + (l & 15);
    bool ok = arow < NTYPES_PAD;
    bf16x8 a[4];
#pragma unroll
    for (int ks = 0; ks < 4; ++ks) {
      BF8 av;
      const float* ap = emb + (size_t)arow * FDIM + (l >> 4) * 8 + ks * 32;
#pragma unroll
      for (int i = 0; i < 8; ++i) av.u[i] = ok ? f2bf(ap[i]) : 0;
      a[ks] = av.v;
    }
    __syncthreads();
    f32x4 acc[8] = {};
#pragma unroll
    for (int ks = 0; ks < 4; ++ks) {
#pragma unroll
      for (int ct = 0; ct < 8; ++ct) {
        int n = ct * 16 + (l & 15);
        int kk = (ks * 32 + (l >> 4) * 8) ^ ((n & 15) << 3);
        bf16x8 b = *(const bf16x8*)&Ws[n * 128 + kk];
        acc[ct] =
            __builtin_amdgcn_mfma_f32_16x16x32_bf16(a[ks], b, acc[ct], 0, 0, 0);
      }
    }
#pragma unroll
    for (int ct = 0; ct < 8; ++ct) {
      int col = ct * 16 + (l & 15);
#pragma unroll
      for (int r = 0; r < 4; ++r) {
        int row = row0 + (l >> 4) * 4 + r;
        if (row < NTYPES_PAD) T1[row * FDIM + col] = f2bf(acc[ct][r]);
      }
    }
    return;
  }

  // ---- prep part ----
  int* si = (int*)sh;  // si[0..255] scan, si[256..256+NSB) block sums
  int q = blk * 256 + tid;

  // Zb zero (independent streaming work, rides this launch for free)
  for (int i = blk * 256 + tid; i < N_GRAPHS * FDIM; i += NSB * 256)
    Zb[i] = 0.0f;

  // gstart from sorted batch: this thread covers nodes [4q, 4q+4)
  if (q < NQUAD) {
    int i0 = 4 * q;
    int prev = (i0 == 0) ? -1 : batch[i0 - 1];
#pragma unroll
    for (int k = 0; k < 4; ++k) {
      int i = i0 + k;
      int bb = batch[i];
      for (int g = prev + 1; g <= bb; ++g) gstart[g] = i;
      prev = bb;
    }
    if (i0 + 3 == N_NODES - 1)
      for (int g = prev + 1; g <= N_GRAPHS; ++g) gstart[g] = N_NODES;
  }

  // per-node prefix over the 128 chunk histograms
  unsigned int r0 = 0, r1 = 0, r2 = 0, r3 = 0;
  if (q < NQUAD) {
    for (int b = 0; b < NBLK; ++b) {
      unsigned int v = Hist[(size_t)b * NQUAD + q];
      Cur[(size_t)b * NQUAD + q] =
          (r0 & 255u) | ((r1 & 255u) << 8) | ((r2 & 255u) << 16) | (r3 << 24);
      r0 += v & 255u;
      r1 += (v >> 8) & 255u;
      r2 += (v >> 16) & 255u;
      r3 += v >> 24;
    }
    float4 dv = make_float4(rsqrtf((float)r0 + 1.f), rsqrtf((float)r1 + 1.f),
                            rsqrtf((float)r2 + 1.f), rsqrtf((float)r3 + 1.f));
    ((float4*)dis)[q] = dv;
  }

  // block-level exclusive scan of per-thread sums
  int tsum = (q < NQUAD) ? (int)(r0 + r1 + r2 + r3) : 0;
  si[tid] = tsum;
  __syncthreads();
  for (int d = 1; d < 256; d <<= 1) {
    int u = (tid >= d) ? si[tid - d] : 0;
    __syncthreads();
    si[tid] += u;
    __syncthreads();
  }
  int excl = si[tid] - tsum;
  int btotal = si[255];

  // post + all-posted barrier (device-scope atomics; NSB blocks co-resident)
  if (tid == 0) {
    atomicExch(&g_bsum[blk], btotal);
    __threadfence();
    atomicAdd(g_done, 1);
    while (atomicAdd(g_done, 0) < NSB) {
    }
  }
  __syncthreads();
  int* sb = si + 256;
  if (tid < NSB) sb[tid] = atomicAdd(&g_bsum[tid], 0);
  __syncthreads();
  int bpref = 0;
  for (int t = 0; t < blk; ++t) bpref += sb[t];

  if (q < NQUAD) {
    int base = bpref + excl;
    ((int4*)row_ptr)[q] =
        make_int4(base, base + (int)r0, base + (int)(r0 + r1),
                  base + (int)(r0 + r1 + r2));
  }
  if (q == NQUAD - 1) row_ptr[N_NODES] = N_EDGES;
}

// CSR fill, no atomics. One 8B entry:
//   src(16) | type(16)<<16 | bf16(dis_dst)<<32 | bf16(dis_src)<<48
__global__ __launch_bounds__(512) void k_fill2(
    const int* __restrict__ src, const int* __restrict__ dst,
    const int* __restrict__ x_type, const int* __restrict__ row_ptr,
    const unsigned int* __restrict__ Cur, const unsigned char* __restrict__ rank8,
    const float* __restrict__ dis, unsigned long long* __restrict__ csr) {
  int e = blockIdx.x * blockDim.x + threadIdx.x;
  if (e >= N_EDGES) return;
  int b = e / CHUNK;
  int s = src[e], d = dst[e];
  unsigned int cw = Cur[(size_t)b * NQUAD + (d >> 2)];
  int base = (int)((cw >> ((d & 3) * 8)) & 0xFFu);
  int pos = row_ptr[d] + base + (int)rank8[e];
  unsigned int lo = (unsigned int)s | ((unsigned int)x_type[s] << 16);
  unsigned int hi = (unsigned int)f2bf(dis[d]) |
                    ((unsigned int)f2bf(dis[s]) << 16);
  csr[pos] = (unsigned long long)lo | ((unsigned long long)hi << 32);
}

// Layer 1: 1 wave/node, unroll 8/4/1 ladder. Edge weight (bf16 dis_src) is
// carried IN the csr entry -> single 8B uniform load per edge, no dis gather.
// ytilde = di * relu(di*(di*T1[type_d] + sum dis_s*T1[type_s]) + b1).
__global__ void k_agg1(const int* __restrict__ x_type,
                       const unsigned short* __restrict__ T1,
                       const float* __restrict__ b1,
                       const int* __restrict__ row_ptr,
                       const unsigned long long* __restrict__ csr,
                       const float* __restrict__ dis,
                       unsigned int* __restrict__ y1) {
  int gid = blockIdx.x * blockDim.x + threadIdx.x;
  int node = gid >> 6;
  int lane = gid & 63;
  if (node >= N_NODES) return;
  const unsigned int* T = (const unsigned int*)T1;
  float di = dis[node];
  unsigned int v = T[(size_t)x_type[node] * 64 + lane];
  float ax = bflo(v) * di, ay = bfhi(v) * di;
  int j = row_ptr[node], end = row_ptr[node + 1];
  for (; j + 8 <= end; j += 8) {
    unsigned long long E0 = csr[j], E1 = csr[j + 1];
    unsigned long long E2 = csr[j + 2], E3 = csr[j + 3];
    unsigned long long E4 = csr[j + 4], E5 = csr[j + 5];
    unsigned long long E6 = csr[j + 6], E7 = csr[j + 7];
    unsigned int u0 = T[(size_t)(((unsigned int)E0) >> 16) * 64 + lane];
    unsigned int u1 = T[(size_t)(((unsigned int)E1) >> 16) * 64 + lane];
    unsigned int u2 = T[(size_t)(((unsigned int)E2) >> 16) * 64 + lane];
    unsigned int u3 = T[(size_t)(((unsigned int)E3) >> 16) * 64 + lane];
    unsigned int u4 = T[(size_t)(((unsigned int)E4) >> 16) * 64 + lane];
    unsigned int u5 = T[(size_t)(((unsigned int)E5) >> 16) * 64 + lane];
    unsigned int u6 = T[(size_t)(((unsigned int)E6) >> 16) * 64 + lane];
    unsigned int u7 = T[(size_t)(((unsigned int)E7) >> 16) * 64 + lane];
    float n0 = __uint_as_float((unsigned int)(E0 >> 48) << 16);
    float n1 = __uint_as_float((unsigned int)(E1 >> 48) << 16);
    float n2 = __uint_as_float((unsigned int)(E2 >> 48) << 16);
    float n3 = __uint_as_float((unsigned int)(E3 >> 48) << 16);
    float n4 = __uint_as_float((unsigned int)(E4 >> 48) << 16);
    float n5 = __uint_as_float((unsigned int)(E5 >> 48) << 16);
    float n6 = __uint_as_float((unsigned int)(E6 >> 48) << 16);
    float n7 = __uint_as_float((unsigned int)(E7 >> 48) << 16);
    ax = fmaf(bflo(u0), n0, ax); ay = fmaf(bfhi(u0), n0, ay);
    ax = fmaf(bflo(u1), n1, ax); ay = fmaf(bfhi(u1), n1, ay);
    ax = fmaf(bflo(u2), n2, ax); ay = fmaf(bfhi(u2), n2, ay);
    ax = fmaf(bflo(u3), n3, ax); ay = fmaf(bfhi(u3), n3, ay);
    ax = fmaf(bflo(u4), n4, ax); ay = fmaf(bfhi(u4), n4, ay);
    ax = fmaf(bflo(u5), n5, ax); ay = fmaf(bfhi(u5), n5, ay);
    ax = fmaf(bflo(u6), n6, ax); ay = fmaf(bfhi(u6), n6, ay);
    ax = fmaf(bflo(u7), n7, ax); ay = fmaf(bfhi(u7), n7, ay);
  }
  for (; j + 4 <= end; j += 4) {
    unsigned long long E0 = csr[j], E1 = csr[j + 1];
    unsigned long long E2 = csr[j + 2], E3 = csr[j + 3];
    unsigned int u0 = T[(size_t)(((unsigned int)E0) >> 16) * 64 + lane];
    unsigned int u1 = T[(size_t)(((unsigned int)E1) >> 16) * 64 + lane];
    unsigned int u2 = T[(size_t)(((unsigned int)E2) >> 16) * 64 + lane];
    unsigned int u3 = T[(size_t)(((unsigned int)E3) >> 16) * 64 + lane];
    float n0 = __uint_as_float((unsigned int)(E0 >> 48) << 16);
    float n1 = __uint_as_float((unsigned int)(E1 >> 48) << 16);
    float n2 = __uint_as_float((unsigned int)(E2 >> 48) << 16);
    float n3 = __uint_as_float((unsigned int)(E3 >> 48) << 16);
    ax = fmaf(bflo(u0), n0, ax); ay = fmaf(bfhi(u0), n0, ay);
    ax = fmaf(bflo(u1), n1, ax); ay = fmaf(bfhi(u1), n1, ay);
    ax = fmaf(bflo(u2), n2, ax); ay = fmaf(bfhi(u2), n2, ay);
    ax = fmaf(bflo(u3), n3, ax); ay = fmaf(bfhi(u3), n3, ay);
  }
  for (; j < end; ++j) {
    unsigned long long E = csr[j];
    unsigned int u = T[(size_t)(((unsigned int)E) >> 16) * 64 + lane];
    float nw = __uint_as_float((unsigned int)(E >> 48) << 16);
    ax = fmaf(bflo(u), nw, ax);
    ay = fmaf(bfhi(u), nw, ay);
  }
  float2 bb = ((const float2*)b1)[lane];
  ax = fmaxf(fmaf(di, ax, bb.x), 0.f) * di;
  ay = fmaxf(fmaf(di, ay, bb.y), 0.f) * di;
  y1[(size_t)node * 64 + lane] = (unsigned int)f2bf(ax) |
                                 ((unsigned int)f2bf(ay) << 16);
}

// Pooled layer 2 (best measured ladder): per graph-run the csr range is
// CONTIGUOUS -> flat gather loop, unroll 16/4/1 (w = bf16 dis_dst in entry
// bits [47:32]). First run -> bf16-packed Partials; later runs -> Zb.
__global__ void k_aggpool(const unsigned int* __restrict__ y1,
                          const int* __restrict__ row_ptr,
                          const unsigned long long* __restrict__ csr,
                          const float* __restrict__ dis,
                          const int* __restrict__ batch,
                          unsigned int* __restrict__ Partials,
                          int* __restrict__ Gid, float* __restrict__ Zb) {
  int gid = blockIdx.x * blockDim.x + threadIdx.x;
  int wid = gid >> 6;
  int lane = gid & 63;
  int n0 = wid * NPW;
  if (n0 >= N_NODES) return;
  int nend = min(n0 + NPW, N_NODES);
  int g0 = batch[n0];
  float px = 0.f, py = 0.f;
  int node = n0;
  while (node < nend) {
    int g = batch[node];
    int rend = node + 1;
    while (rend < nend && batch[rend] == g) ++rend;  // run [node, rend)
    float sx = 0.f, sy = 0.f;
    for (int n = node; n < rend; ++n) {  // self-loop terms
      float dn = dis[n];
      unsigned int v = y1[(size_t)n * 64 + lane];
      sx = fmaf(dn, bflo(v), sx);
      sy = fmaf(dn, bfhi(v), sy);
    }
    int j = row_ptr[node], jend = row_ptr[rend];
    for (; j + 16 <= jend; j += 16) {
#pragma unroll
      for (int k = 0; k < 16; ++k) {
        unsigned long long e = csr[j + k];
        unsigned int u = y1[(size_t)(e & 0xFFFFu) * 64 + lane];
        float w = __uint_as_float(((unsigned int)(e >> 32) & 0xFFFFu) << 16);
        sx = fmaf(bflo(u), w, sx);
        sy = fmaf(bfhi(u), w, sy);
      }
    }
    for (; j + 4 <= jend; j += 4) {
#pragma unroll
      for (int k = 0; k < 4; ++k) {
        unsigned long long e = csr[j + k];
        unsigned int u = y1[(size_t)(e & 0xFFFFu) * 64 + lane];
        float w = __uint_as_float(((unsigned int)(e >> 32) & 0xFFFFu) << 16);
        sx = fmaf(bflo(u), w, sx);
        sy = fmaf(bfhi(u), w, sy);
      }
    }
    for (; j < jend; ++j) {
      unsigned long long e = csr[j];
      unsigned int u = y1[(size_t)(e & 0xFFFFu) * 64 + lane];
      float w = __uint_as_float(((unsigned int)(e >> 32) & 0xFFFFu) << 16);
      sx = fmaf(bflo(u), w, sx);
      sy = fmaf(bfhi(u), w, sy);
    }
    if (g == g0) {
      px += sx;
      py += sy;
    } else {
      atomicAdd(&Zb[(size_t)g * FDIM + 2 * lane], sx);
      atomicAdd(&Zb[(size_t)g * FDIM + 2 * lane + 1], sy);
    }
    node = rend;
  }
  Partials[(size_t)wid * 64 + lane] =
      (unsigned int)f2bf(px) | ((unsigned int)f2bf(py) << 16);
  if (lane == 0) Gid[wid] = g0;
}

// Reduce bf16 partials + Zb -> Z[g]; out[g] = Z@W2 + nodecount*b2.
__global__ __launch_bounds__(128) void k_poolzw2(
    const unsigned int* __restrict__ Partials, const int* __restrict__ Gid,
    const float* __restrict__ Zb, const int* __restrict__ gstart,
    const float* __restrict__ W2, const float* __restrict__ b2,
    float* __restrict__ out) {
  __shared__ float Zs[FDIM];
  int g = blockIdx.x, t = threadIdx.x;
  int s = gstart[g], e = gstart[g + 1];
  float acc = Zb[(size_t)g * FDIM + t];
  if (e > s) {
    int w0 = s / NPW, w1 = (e - 1) / NPW;
    int half = t & 1, pl = t >> 1;
    for (int w = w0; w <= w1; ++w)
      if (Gid[w] == g) {
        unsigned int pv = Partials[(size_t)w * 64 + pl];
        acc += half ? bfhi(pv) : bflo(pv);
      }
  }
  Zs[t] = acc;
  __syncthreads();
  float o = 0.f;
#pragma unroll 8
  for (int k = 0; k < FDIM; ++k) o = fmaf(Zs[k], W2[k * FDIM + t], o);
  out[(size_t)g * FDIM + t] = o + (float)(e - s) * b2[t];
}

extern "C" void kernel_launch(void* const* d_in, const int* in_sizes, int n_in,
                              void* d_out, int out_size, void* d_ws,
                              size_t ws_size, hipStream_t stream) {
  const int* x_type = (const int*)d_in[0];
  const int* edge_index = (const int*)d_in[1];
  const int* batch = (const int*)d_in[2];
  const float* emb = (const float*)d_in[3];
  const float* W1 = (const float*)d_in[4];
  const float* b1 = (const float*)d_in[5];
  const float* W2 = (const float*)d_in[6];
  const float* b2 = (const float*)d_in[7];
  float* out = (float*)d_out;

  const int* src = edge_index;
  const int* dst = edge_index + N_EDGES;

  char* p = (char*)d_ws;
  size_t off = 0;
  auto alloc = [&](size_t bytes) {
    void* r = p + off;
    off = (off + bytes + 255) & ~(size_t)255;
    return r;
  };
  float* dis = (float*)alloc(N_NODES * 4);
  int* row_ptr = (int*)alloc((N_NODES + 1) * 4);
  int* gstart = (int*)alloc((N_GRAPHS + 1) * 4);
  unsigned int* Hist = (unsigned int*)alloc((size_t)NBLK * NQUAD * 4);
  unsigned int* Cur = (unsigned int*)alloc((size_t)NBLK * NQUAD * 4);
  unsigned char* rank8 = (unsigned char*)alloc(N_EDGES);
  unsigned long long* csr =
      (unsigned long long*)alloc((size_t)N_EDGES * 8);
  unsigned short* T1 = (unsigned short*)alloc((size_t)NTYPES_PAD * FDIM * 2);
  unsigned int* y1 = (unsigned int*)alloc((size_t)N_NODES * 64 * 4);
  unsigned int* Partials = (unsigned int*)alloc((size_t)NW * 64 * 4);
  int* Gid = (int*)alloc(NW * 4);
  float* Zb = (float*)alloc((size_t)N_GRAPHS * FDIM * 4);
  int* g_bsum = (int*)alloc(NSB * 4);
  int* g_done = (int*)alloc(4);
  (void)ws_size;

  k_hist<<<NBLK, 512, 0, stream>>>(dst, Hist, rank8, g_done);
  k_prep<<<NSB + EMBW_BLOCKS, 256, 0, stream>>>(
      Hist, batch, Cur, dis, row_ptr, Zb, gstart, g_bsum, g_done, emb, W1, T1);
  k_fill2<<<(N_EDGES + 511) / 512, 512, 0, stream>>>(
      src, dst, x_type, row_ptr, Cur, rank8, dis, csr);
  k_agg1<<<(N_NODES * 64 + 255) / 256, 256, 0, stream>>>(
      x_type, T1, b1, row_ptr, csr, dis, y1);
  k_aggpool<<<(NW * 64 + 255) / 256, 256, 0, stream>>>(
      y1, row_ptr, csr, dis, batch, Partials, Gid, Zb);
  k_poolzw2<<<N_GRAPHS, 128, 0, stream>>>(Partials, Gid, Zb, gstart, W2, b2,
                                          out);
}

// Round 16
// 146.505 us; speedup vs baseline: 1.0195x; 1.0195x over previous
//
#include <hip/hip_runtime.h>

#define N_NODES 50000
#define N_EDGES 800000
#define N_GRAPHS 512
#define FDIM 128
#define NTYPES_PAD 1000

#define NBLK 128
#define CHUNK ((N_EDGES + NBLK - 1) / NBLK)  // 6250
#define NQUAD (N_NODES / 4)                  // 12500
#define NSB ((NQUAD + 255) / 256)            // 49 scan blocks in k_prep
#define EMBW_BLOCKS 16
#define NPW 2
#define NW ((N_NODES + NPW - 1) / NPW)       // 25000

typedef __bf16 bf16x8 __attribute__((ext_vector_type(8)));
typedef float f32x4 __attribute__((ext_vector_type(4)));
union BF8 { bf16x8 v; unsigned short u[8]; };

__device__ __forceinline__ unsigned short f2bf(float f) {
  unsigned int u = __float_as_uint(f);
  unsigned int r = (u + 0x7FFFu + ((u >> 16) & 1u)) >> 16;
  return (unsigned short)r;
}
__device__ __forceinline__ float bflo(unsigned int v) {
  return __uint_as_float(v << 16);
}
__device__ __forceinline__ float bfhi(unsigned int v) {
  return __uint_as_float(v & 0xFFFF0000u);
}

// Per-chunk LDS histogram (8-bit packed); emits per-edge local rank.
// Also resets k_prep's done-counter for this launch (graph replays).
__global__ __launch_bounds__(512) void k_hist(const int* __restrict__ dst,
                                              unsigned int* __restrict__ Hist,
                                              unsigned char* __restrict__ rank8,
                                              int* __restrict__ g_done) {
  __shared__ unsigned int h[NQUAD];  // 50 KB
  int b = blockIdx.x, t = threadIdx.x;
  if (b == 0 && t == 0) *g_done = 0;
  for (int i = t; i < NQUAD; i += 512) h[i] = 0;
  __syncthreads();
  int e0 = b * CHUNK, e1 = min(e0 + CHUNK, N_EDGES);
  for (int e = e0 + t; e < e1; e += 512) {
    int d = dst[e];
    unsigned int sh = (d & 3) * 8;
    unsigned int old = atomicAdd(&h[d >> 2], 1u << sh);
    rank8[e] = (unsigned char)((old >> sh) & 0xFFu);
  }
  __syncthreads();
  unsigned int* H = Hist + (size_t)b * NQUAD;
  for (int i = t; i < NQUAD; i += 512) H[i] = h[i];
}

// Fused kernel: blocks [0,NSB) do the scan/prep work (Cur bases, dis,
// row_ptr via device-scope all-posted barrier, Zb zero, gstart); blocks
// [NSB, NSB+EMBW_BLOCKS) compute T1 = emb @ W1 (independent work).
__global__ __launch_bounds__(256) void k_prep(
    const unsigned int* __restrict__ Hist, const int* __restrict__ batch,
    unsigned int* __restrict__ Cur, float* __restrict__ dis,
    int* __restrict__ row_ptr, float* __restrict__ Zb,
    int* __restrict__ gstart, int* __restrict__ g_bsum,
    int* __restrict__ g_done, const float* __restrict__ emb,
    const float* __restrict__ W1, unsigned short* __restrict__ T1) {
  __shared__ unsigned short sh[16384];  // 32 KB union (embw Ws / prep scan)
  int blk = blockIdx.x, tid = threadIdx.x;

  if (blk >= NSB) {
    // ---- embw part: T1 = emb @ W1, swizzled bf16 W in LDS ----
    unsigned short* Ws = sh;
    int t = tid, w = t >> 6, l = t & 63;
    for (int i = t; i < 16384; i += 256) {
      int k = i >> 7, n = i & 127;
      Ws[n * 128 + (k ^ ((n & 15) << 3))] = f2bf(W1[i]);
    }
    int row0 = (blk - NSB) * 64 + w * 16;
    int arow = row0 + (l & 15);
    bool ok = arow < NTYPES_PAD;
    bf16x8 a[4];
#pragma unroll
    for (int ks = 0; ks < 4; ++ks) {
      BF8 av;
      const float* ap = emb + (size_t)arow * FDIM + (l >> 4) * 8 + ks * 32;
#pragma unroll
      for (int i = 0; i < 8; ++i) av.u[i] = ok ? f2bf(ap[i]) : 0;
      a[ks] = av.v;
    }
    __syncthreads();
    f32x4 acc[8] = {};
#pragma unroll
    for (int ks = 0; ks < 4; ++ks) {
#pragma unroll
      for (int ct = 0; ct < 8; ++ct) {
        int n = ct * 16 + (l & 15);
        int kk = (ks * 32 + (l >> 4) * 8) ^ ((n & 15) << 3);
        bf16x8 b = *(const bf16x8*)&Ws[n * 128 + kk];
        acc[ct] =
            __builtin_amdgcn_mfma_f32_16x16x32_bf16(a[ks], b, acc[ct], 0, 0, 0);
      }
    }
#pragma unroll
    for (int ct = 0; ct < 8; ++ct) {
      int col = ct * 16 + (l & 15);
#pragma unroll
      for (int r = 0; r < 4; ++r) {
        int row = row0 + (l >> 4) * 4 + r;
        if (row < NTYPES_PAD) T1[row * FDIM + col] = f2bf(acc[ct][r]);
      }
    }
    return;
  }

  // ---- prep part ----
  int* si = (int*)sh;  // si[0..255] scan, si[256..256+NSB) block sums
  int q = blk * 256 + tid;

  // Zb zero (independent streaming work, rides this launch for free)
  for (int i = blk * 256 + tid; i < N_GRAPHS * FDIM; i += NSB * 256)
    Zb[i] = 0.0f;

  // gstart from sorted batch: this thread covers nodes [4q, 4q+4)
  if (q < NQUAD) {
    int i0 = 4 * q;
    int prev = (i0 == 0) ? -1 : batch[i0 - 1];
#pragma unroll
    for (int k = 0; k < 4; ++k) {
      int i = i0 + k;
      int bb = batch[i];
      for (int g = prev + 1; g <= bb; ++g) gstart[g] = i;
      prev = bb;
    }
    if (i0 + 3 == N_NODES - 1)
      for (int g = prev + 1; g <= N_GRAPHS; ++g) gstart[g] = N_NODES;
  }

  // per-node prefix over the 128 chunk histograms
  unsigned int r0 = 0, r1 = 0, r2 = 0, r3 = 0;
  if (q < NQUAD) {
    for (int b = 0; b < NBLK; ++b) {
      unsigned int v = Hist[(size_t)b * NQUAD + q];
      Cur[(size_t)b * NQUAD + q] =
          (r0 & 255u) | ((r1 & 255u) << 8) | ((r2 & 255u) << 16) | (r3 << 24);
      r0 += v & 255u;
      r1 += (v >> 8) & 255u;
      r2 += (v >> 16) & 255u;
      r3 += v >> 24;
    }
    float4 dv = make_float4(rsqrtf((float)r0 + 1.f), rsqrtf((float)r1 + 1.f),
                            rsqrtf((float)r2 + 1.f), rsqrtf((float)r3 + 1.f));
    ((float4*)dis)[q] = dv;
  }

  // block-level exclusive scan of per-thread sums
  int tsum = (q < NQUAD) ? (int)(r0 + r1 + r2 + r3) : 0;
  si[tid] = tsum;
  __syncthreads();
  for (int d = 1; d < 256; d <<= 1) {
    int u = (tid >= d) ? si[tid - d] : 0;
    __syncthreads();
    si[tid] += u;
    __syncthreads();
  }
  int excl = si[tid] - tsum;
  int btotal = si[255];

  // post + all-posted barrier (device-scope atomics; NSB blocks co-resident)
  if (tid == 0) {
    atomicExch(&g_bsum[blk], btotal);
    __threadfence();
    atomicAdd(g_done, 1);
    while (atomicAdd(g_done, 0) < NSB) {
    }
  }
  __syncthreads();
  int* sb = si + 256;
  if (tid < NSB) sb[tid] = atomicAdd(&g_bsum[tid], 0);
  __syncthreads();
  int bpref = 0;
  for (int t = 0; t < blk; ++t) bpref += sb[t];

  if (q < NQUAD) {
    int base = bpref + excl;
    ((int4*)row_ptr)[q] =
        make_int4(base, base + (int)r0, base + (int)(r0 + r1),
                  base + (int)(r0 + r1 + r2));
  }
  if (q == NQUAD - 1) row_ptr[N_NODES] = N_EDGES;
}

// CSR fill, no atomics. One 8B entry: src | type<<16 | bf16(dis_dst)<<32.
__global__ __launch_bounds__(512) void k_fill2(
    const int* __restrict__ src, const int* __restrict__ dst,
    const int* __restrict__ x_type, const int* __restrict__ row_ptr,
    const unsigned int* __restrict__ Cur, const unsigned char* __restrict__ rank8,
    const float* __restrict__ dis, unsigned long long* __restrict__ csr) {
  int e = blockIdx.x * blockDim.x + threadIdx.x;
  if (e >= N_EDGES) return;
  int b = e / CHUNK;
  int s = src[e], d = dst[e];
  unsigned int cw = Cur[(size_t)b * NQUAD + (d >> 2)];
  int base = (int)((cw >> ((d & 3) * 8)) & 0xFFu);
  int pos = row_ptr[d] + base + (int)rank8[e];
  unsigned int lo = (unsigned int)s | ((unsigned int)x_type[s] << 16);
  unsigned int hi = (unsigned int)f2bf(dis[d]);
  csr[pos] = (unsigned long long)lo | ((unsigned long long)hi << 32);
}

// Layer 1 (best measured): 1 wave/node, unroll 8/4/1 ladder.
// ytilde = di * relu(di*(di*T1[type_d] + sum dis_s*T1[type_s]) + b1).
__global__ void k_agg1(const int* __restrict__ x_type,
                       const unsigned short* __restrict__ T1,
                       const float* __restrict__ b1,
                       const int* __restrict__ row_ptr,
                       const unsigned long long* __restrict__ csr,
                       const float* __restrict__ dis,
                       unsigned int* __restrict__ y1) {
  int gid = blockIdx.x * blockDim.x + threadIdx.x;
  int node = gid >> 6;
  int lane = gid & 63;
  if (node >= N_NODES) return;
  const unsigned int* T = (const unsigned int*)T1;
  const unsigned int* C = (const unsigned int*)csr;  // lo words at even idx
  float di = dis[node];
  unsigned int v = T[(size_t)x_type[node] * 64 + lane];
  float ax = bflo(v) * di, ay = bfhi(v) * di;
  int j = row_ptr[node], end = row_ptr[node + 1];
  for (; j + 8 <= end; j += 8) {
    unsigned int e0 = C[2 * j], e1 = C[2 * j + 2];
    unsigned int e2 = C[2 * j + 4], e3 = C[2 * j + 6];
    unsigned int e4 = C[2 * j + 8], e5 = C[2 * j + 10];
    unsigned int e6 = C[2 * j + 12], e7 = C[2 * j + 14];
    unsigned int u0 = T[(size_t)(e0 >> 16) * 64 + lane];
    unsigned int u1 = T[(size_t)(e1 >> 16) * 64 + lane];
    unsigned int u2 = T[(size_t)(e2 >> 16) * 64 + lane];
    unsigned int u3 = T[(size_t)(e3 >> 16) * 64 + lane];
    unsigned int u4 = T[(size_t)(e4 >> 16) * 64 + lane];
    unsigned int u5 = T[(size_t)(e5 >> 16) * 64 + lane];
    unsigned int u6 = T[(size_t)(e6 >> 16) * 64 + lane];
    unsigned int u7 = T[(size_t)(e7 >> 16) * 64 + lane];
    float n0 = dis[e0 & 0xFFFFu], n1 = dis[e1 & 0xFFFFu];
    float n2 = dis[e2 & 0xFFFFu], n3 = dis[e3 & 0xFFFFu];
    float n4 = dis[e4 & 0xFFFFu], n5 = dis[e5 & 0xFFFFu];
    float n6 = dis[e6 & 0xFFFFu], n7 = dis[e7 & 0xFFFFu];
    ax = fmaf(bflo(u0), n0, ax); ay = fmaf(bfhi(u0), n0, ay);
    ax = fmaf(bflo(u1), n1, ax); ay = fmaf(bfhi(u1), n1, ay);
    ax = fmaf(bflo(u2), n2, ax); ay = fmaf(bfhi(u2), n2, ay);
    ax = fmaf(bflo(u3), n3, ax); ay = fmaf(bfhi(u3), n3, ay);
    ax = fmaf(bflo(u4), n4, ax); ay = fmaf(bfhi(u4), n4, ay);
    ax = fmaf(bflo(u5), n5, ax); ay = fmaf(bfhi(u5), n5, ay);
    ax = fmaf(bflo(u6), n6, ax); ay = fmaf(bfhi(u6), n6, ay);
    ax = fmaf(bflo(u7), n7, ax); ay = fmaf(bfhi(u7), n7, ay);
  }
  for (; j + 4 <= end; j += 4) {
    unsigned int e0 = C[2 * j], e1 = C[2 * j + 2];
    unsigned int e2 = C[2 * j + 4], e3 = C[2 * j + 6];
    unsigned int u0 = T[(size_t)(e0 >> 16) * 64 + lane];
    unsigned int u1 = T[(size_t)(e1 >> 16) * 64 + lane];
    unsigned int u2 = T[(size_t)(e2 >> 16) * 64 + lane];
    unsigned int u3 = T[(size_t)(e3 >> 16) * 64 + lane];
    float n0 = dis[e0 & 0xFFFFu], n1 = dis[e1 & 0xFFFFu];
    float n2 = dis[e2 & 0xFFFFu], n3 = dis[e3 & 0xFFFFu];
    ax = fmaf(bflo(u0), n0, ax); ay = fmaf(bfhi(u0), n0, ay);
    ax = fmaf(bflo(u1), n1, ax); ay = fmaf(bfhi(u1), n1, ay);
    ax = fmaf(bflo(u2), n2, ax); ay = fmaf(bfhi(u2), n2, ay);
    ax = fmaf(bflo(u3), n3, ax); ay = fmaf(bfhi(u3), n3, ay);
  }
  for (; j < end; ++j) {
    unsigned int e = C[2 * j];
    unsigned int u = T[(size_t)(e >> 16) * 64 + lane];
    float nw = dis[e & 0xFFFFu];
    ax = fmaf(bflo(u), nw, ax);
    ay = fmaf(bfhi(u), nw, ay);
  }
  float2 bb = ((const float2*)b1)[lane];
  ax = fmaxf(fmaf(di, ax, bb.x), 0.f) * di;
  ay = fmaxf(fmaf(di, ay, bb.y), 0.f) * di;
  y1[(size_t)node * 64 + lane] = (unsigned int)f2bf(ax) |
                                 ((unsigned int)f2bf(ay) << 16);
}

// Pooled layer 2 (best measured ladder): per graph-run the csr range is
// CONTIGUOUS -> flat gather loop, unroll 16/4/1. First run -> bf16-packed
// Partials; later runs (rare) -> Zb atomics.
__global__ void k_aggpool(const unsigned int* __restrict__ y1,
                          const int* __restrict__ row_ptr,
                          const unsigned long long* __restrict__ csr,
                          const float* __restrict__ dis,
                          const int* __restrict__ batch,
                          unsigned int* __restrict__ Partials,
                          int* __restrict__ Gid, float* __restrict__ Zb) {
  int gid = blockIdx.x * blockDim.x + threadIdx.x;
  int wid = gid >> 6;
  int lane = gid & 63;
  int n0 = wid * NPW;
  if (n0 >= N_NODES) return;
  int nend = min(n0 + NPW, N_NODES);
  int g0 = batch[n0];
  float px = 0.f, py = 0.f;
  int node = n0;
  while (node < nend) {
    int g = batch[node];
    int rend = node + 1;
    while (rend < nend && batch[rend] == g) ++rend;  // run [node, rend)
    float sx = 0.f, sy = 0.f;
    for (int n = node; n < rend; ++n) {  // self-loop terms
      float dn = dis[n];
      unsigned int v = y1[(size_t)n * 64 + lane];
      sx = fmaf(dn, bflo(v), sx);
      sy = fmaf(dn, bfhi(v), sy);
    }
    int j = row_ptr[node], jend = row_ptr[rend];
    for (; j + 16 <= jend; j += 16) {
#pragma unroll
      for (int k = 0; k < 16; ++k) {
        unsigned long long e = csr[j + k];
        unsigned int u = y1[(size_t)(e & 0xFFFFu) * 64 + lane];
        float w = __uint_as_float(((unsigned int)(e >> 32)) << 16);
        sx = fmaf(bflo(u), w, sx);
        sy = fmaf(bfhi(u), w, sy);
      }
    }
    for (; j + 4 <= jend; j += 4) {
#pragma unroll
      for (int k = 0; k < 4; ++k) {
        unsigned long long e = csr[j + k];
        unsigned int u = y1[(size_t)(e & 0xFFFFu) * 64 + lane];
        float w = __uint_as_float(((unsigned int)(e >> 32)) << 16);
        sx = fmaf(bflo(u), w, sx);
        sy = fmaf(bfhi(u), w, sy);
      }
    }
    for (; j < jend; ++j) {
      unsigned long long e = csr[j];
      unsigned int u = y1[(size_t)(e & 0xFFFFu) * 64 + lane];
      float w = __uint_as_float(((unsigned int)(e >> 32)) << 16);
      sx = fmaf(bflo(u), w, sx);
      sy = fmaf(bfhi(u), w, sy);
    }
    if (g == g0) {
      px += sx;
      py += sy;
    } else {
      atomicAdd(&Zb[(size_t)g * FDIM + 2 * lane], sx);
      atomicAdd(&Zb[(size_t)g * FDIM + 2 * lane + 1], sy);
    }
    node = rend;
  }
  Partials[(size_t)wid * 64 + lane] =
      (unsigned int)f2bf(px) | ((unsigned int)f2bf(py) << 16);
  if (lane == 0) Gid[wid] = g0;
}

// Reduce bf16 partials + Zb -> Z[g]; out[g] = Z@W2 + nodecount*b2.
__global__ __launch_bounds__(128) void k_poolzw2(
    const unsigned int* __restrict__ Partials, const int* __restrict__ Gid,
    const float* __restrict__ Zb, const int* __restrict__ gstart,
    const float* __restrict__ W2, const float* __restrict__ b2,
    float* __restrict__ out) {
  __shared__ float Zs[FDIM];
  int g = blockIdx.x, t = threadIdx.x;
  int s = gstart[g], e = gstart[g + 1];
  float acc = Zb[(size_t)g * FDIM + t];
  if (e > s) {
    int w0 = s / NPW, w1 = (e - 1) / NPW;
    int half = t & 1, pl = t >> 1;
    for (int w = w0; w <= w1; ++w)
      if (Gid[w] == g) {
        unsigned int pv = Partials[(size_t)w * 64 + pl];
        acc += half ? bfhi(pv) : bflo(pv);
      }
  }
  Zs[t] = acc;
  __syncthreads();
  float o = 0.f;
#pragma unroll 8
  for (int k = 0; k < FDIM; ++k) o = fmaf(Zs[k], W2[k * FDIM + t], o);
  out[(size_t)g * FDIM + t] = o + (float)(e - s) * b2[t];
}

extern "C" void kernel_launch(void* const* d_in, const int* in_sizes, int n_in,
                              void* d_out, int out_size, void* d_ws,
                              size_t ws_size, hipStream_t stream) {
  const int* x_type = (const int*)d_in[0];
  const int* edge_index = (const int*)d_in[1];
  const int* batch = (const int*)d_in[2];
  const float* emb = (const float*)d_in[3];
  const float* W1 = (const float*)d_in[4];
  const float* b1 = (const float*)d_in[5];
  const float* W2 = (const float*)d_in[6];
  const float* b2 = (const float*)d_in[7];
  float* out = (float*)d_out;

  const int* src = edge_index;
  const int* dst = edge_index + N_EDGES;

  char* p = (char*)d_ws;
  size_t off = 0;
  auto alloc = [&](size_t bytes) {
    void* r = p + off;
    off = (off + bytes + 255) & ~(size_t)255;
    return r;
  };
  float* dis = (float*)alloc(N_NODES * 4);
  int* row_ptr = (int*)alloc((N_NODES + 1) * 4);
  int* gstart = (int*)alloc((N_GRAPHS + 1) * 4);
  unsigned int* Hist = (unsigned int*)alloc((size_t)NBLK * NQUAD * 4);
  unsigned int* Cur = (unsigned int*)alloc((size_t)NBLK * NQUAD * 4);
  unsigned char* rank8 = (unsigned char*)alloc(N_EDGES);
  unsigned long long* csr =
      (unsigned long long*)alloc((size_t)N_EDGES * 8);
  unsigned short* T1 = (unsigned short*)alloc((size_t)NTYPES_PAD * FDIM * 2);
  unsigned int* y1 = (unsigned int*)alloc((size_t)N_NODES * 64 * 4);
  unsigned int* Partials = (unsigned int*)alloc((size_t)NW * 64 * 4);
  int* Gid = (int*)alloc(NW * 4);
  float* Zb = (float*)alloc((size_t)N_GRAPHS * FDIM * 4);
  int* g_bsum = (int*)alloc(NSB * 4);
  int* g_done = (int*)alloc(4);
  (void)ws_size;

  k_hist<<<NBLK, 512, 0, stream>>>(dst, Hist, rank8, g_done);
  k_prep<<<NSB + EMBW_BLOCKS, 256, 0, stream>>>(
      Hist, batch, Cur, dis, row_ptr, Zb, gstart, g_bsum, g_done, emb, W1, T1);
  k_fill2<<<(N_EDGES + 511) / 512, 512, 0, stream>>>(
      src, dst, x_type, row_ptr, Cur, rank8, dis, csr);
  k_agg1<<<(N_NODES * 64 + 255) / 256, 256, 0, stream>>>(
      x_type, T1, b1, row_ptr, csr, dis, y1);
  k_aggpool<<<(NW * 64 + 255) / 256, 256, 0, stream>>>(
      y1, row_ptr, csr, dis, batch, Partials, Gid, Zb);
  k_poolzw2<<<N_GRAPHS, 128, 0, stream>>>(Partials, Gid, Zb, gstart, W2, b2,
                                          out);
}